// Round 4
// baseline (1118.669 us; speedup 1.0000x reference)
//
#include <hip/hip_runtime.h>

typedef unsigned int uint32;
typedef __attribute__((ext_vector_type(8))) short bf16x8;
typedef __attribute__((ext_vector_type(4))) float f32x4;

// ---------------------------------------------------------------------------
// Sizes: B=2, L=256, E=512, H=8, D=64.  SCALE = 0.125
// ---------------------------------------------------------------------------

// ===========================================================================
// Wr f32 -> bf16 (RNE). 1024x512 = 524288 elems, 4 per thread.
// ===========================================================================
__device__ __forceinline__ uint32 bf_rne(uint32 u) {
  return (u + 0x7fffu + ((u >> 16) & 1u)) >> 16;
}

__global__ void cvt_wr_kernel(const float* __restrict__ Wr, unsigned short* __restrict__ WrBf) {
  int idx = blockIdx.x * 256 + threadIdx.x;   // [0, 131072)
  const uint4* src = (const uint4*)Wr;
  uint4 x = src[idx];
  uint2 o;
  o.x = bf_rne(x.x) | (bf_rne(x.y) << 16);
  o.y = bf_rne(x.z) | (bf_rne(x.w) << 16);
  ((uint2*)WrBf)[idx] = o;
}

// ===========================================================================
// Projection GEMM: Y[m,n] = (sum_k X[m,k] * W[n,k] + bias[n]) * scale
// M=N=K=512.  BM=BN=64, BK=16, 256 threads, 4x4 per thread.
// ===========================================================================
__global__ __launch_bounds__(256) void proj_kernel(
    const float* __restrict__ X0, const float* __restrict__ W0, const float* __restrict__ b0, float* __restrict__ Y0,
    const float* __restrict__ X1, const float* __restrict__ W1, const float* __restrict__ b1, float* __restrict__ Y1,
    const float* __restrict__ X2, const float* __restrict__ W2, const float* __restrict__ b2, float* __restrict__ Y2,
    float scale0) {
  int z = blockIdx.z;
  const float* X = (z == 0) ? X0 : (z == 1) ? X1 : X2;
  const float* W = (z == 0) ? W0 : (z == 1) ? W1 : W2;
  const float* bias = (z == 0) ? b0 : (z == 1) ? b1 : b2;
  float* Y = (z == 0) ? Y0 : (z == 1) ? Y1 : Y2;
  float scale = (z == 0) ? scale0 : 1.0f;

  __shared__ float Xs[16][68];
  __shared__ float Ws[16][68];

  int tid = threadIdx.x;
  int tx = tid & 15, ty = tid >> 4;
  int m0 = blockIdx.x * 64, n0 = blockIdx.y * 64;

  float acc[4][4] = {};

  for (int k0 = 0; k0 < 512; k0 += 16) {
#pragma unroll
    for (int u = 0; u < 4; ++u) {
      int idx = tid + u * 256;           // [0,1024)
      int ml = idx >> 4, kl = idx & 15;
      Xs[kl][ml] = X[(size_t)(m0 + ml) * 512 + k0 + kl];
      Ws[kl][ml] = W[(size_t)(n0 + ml) * 512 + k0 + kl];
    }
    __syncthreads();
#pragma unroll
    for (int kk = 0; kk < 16; ++kk) {
      float4 a = *(const float4*)&Xs[kk][ty * 4];
      float4 w = *(const float4*)&Ws[kk][tx * 4];
      float av[4] = {a.x, a.y, a.z, a.w};
      float wv[4] = {w.x, w.y, w.z, w.w};
#pragma unroll
      for (int i = 0; i < 4; ++i)
#pragma unroll
        for (int jj = 0; jj < 4; ++jj)
          acc[i][jj] += av[i] * wv[jj];
    }
    __syncthreads();
  }
#pragma unroll
  for (int i = 0; i < 4; ++i) {
    int m = m0 + ty * 4 + i;
#pragma unroll
    for (int jj = 0; jj < 4; ++jj) {
      int n = n0 + tx * 4 + jj;
      Y[(size_t)m * 512 + n] = (acc[i][jj] + bias[n]) * scale;
    }
  }
}

// ===========================================================================
// Fused relation-GEMM + score kernel, v4: BARRIER-FREE (wave-autonomous).
// Block = 128 M-rows x 128 N-cols (ONE head). 8192 blocks, 4 waves.
// Wave wv owns rows [wv*32, wv*32+32) x all 128 cols: fully independent.
//  - A (relation f32): coalesced global loads (4 rows x 256B per dwordx4,
//    full cache lines), 1-iter register lookahead, f32->bf16 pack in regs,
//    staged through a WAVE-PRIVATE double-buffered padded LDS tile (pure
//    per-wave transpose engine; ordering via in-wave lgkmcnt, no barrier).
//  - B (Wr bf16, 1 MB, L2-hot): per-lane dwordx4 direct global->reg.
// Col group fc=0..7 within head: even fc -> rq, odd fc -> rk,
// d = (fc>>1)*16 + t15.  acc[2 fr][8 fc].
// Epilogue: wave owns full d-range for its head -> lane-local
// (q+rq)(k+rk) FMA over 4 d-chunks + 16-lane shuffle reduce; direct store.
// NO __syncthreads anywhere.
// ===========================================================================
__global__ __launch_bounds__(256, 3) void rel_score_kernel(
    const float* __restrict__ rel,            // [B][j:256][i:256][512]
    const unsigned short* __restrict__ wrbf,  // [1024][512] bf16
    const float* __restrict__ qws,            // [B*256][512] (pre-scaled)
    const float* __restrict__ kws,            // [B*256][512]
    float* __restrict__ attn)                 // [B][i][j][H] raw scores
{
  __shared__ unsigned short As[4][2][32 * 72];  // [wave][buf][row][k] bf16

  const int tid = threadIdx.x;
  const int lane = tid & 63;
  const int wv = tid >> 6;
  const int blk = blockIdx.x;
  const int head = blk & 7;          // siblings adjacent -> concurrent, L3-shared A
  const int mt2 = blk >> 3;          // (b*256 + j)*2 + ih, [0,1024)
  const int b = mt2 >> 9;
  const int j = (mt2 >> 1) & 255;
  const int ih = mt2 & 1;
  const int i0 = ih * 128 + wv * 32; // this wave's global i base

  // A rows for this wave: rel[(b*256 + j)*256 + i0 + (0..32)][512]
  const float* Abase = rel + (((size_t)(b * 256 + j)) * 256 + i0) * 512;

  const int t15 = lane & 15;
  const int q2 = lane >> 4;          // quad index 0..3
  const int kq = q2 * 8;             // k-chunk for MFMA frags

  // A staging: instr i (0..7): lane covers row 4i+q2, f32 cols t15*4..+4
  const int arow = q2;               // + 4*i
  const int acol = t15 * 4;

  // B: per-lane base (row = head*64 + ... + t15), fc offsets added as consts
  const unsigned short* bbase = wrbf + ((size_t)(head * 64 + t15)) * 512 + kq;

  f32x4 acc[2][8];
#pragma unroll
  for (int fr = 0; fr < 2; ++fr)
#pragma unroll
    for (int fc = 0; fc < 8; ++fc)
      acc[fr][fc] = (f32x4){0.f, 0.f, 0.f, 0.f};

  // ---- prologue: load k-iter 0 A (coalesced) ----
  uint4 a[8];
#pragma unroll
  for (int i = 0; i < 8; ++i)
    a[i] = *(const uint4*)(Abase + (size_t)(4 * i + arow) * 512 + acol);

  for (int k = 0; k < 8; ++k) {
    const int k0 = k * 64;
    unsigned short* asb = &As[wv][k & 1][0];
    // ---- pack prefetched A (f32 truncate -> bf16), write wave-private LDS ----
#pragma unroll
    for (int i = 0; i < 8; ++i) {
      uint2 o;
      o.x = (a[i].y & 0xffff0000u) | (a[i].x >> 16);
      o.y = (a[i].w & 0xffff0000u) | (a[i].z >> 16);
      *(uint2*)&asb[(4 * i + arow) * 72 + acol] = o;
    }
    // ---- prefetch next iter's A (stays in flight through MFMA section) ----
    if (k < 7) {
#pragma unroll
      for (int i = 0; i < 8; ++i)
        a[i] = *(const uint4*)(Abase + (size_t)(4 * i + arow) * 512 + (k0 + 64) + acol);
    }
    // ---- MFMA: read A frags from own LDS, B direct from L2 ----
#pragma unroll
    for (int kh = 0; kh < 2; ++kh) {
      bf16x8 af0 = *(const bf16x8*)&asb[t15 * 72 + kh * 32 + kq];
      bf16x8 af1 = *(const bf16x8*)&asb[(16 + t15) * 72 + kh * 32 + kq];
#pragma unroll
      for (int fc = 0; fc < 8; ++fc) {
        const int ofs = ((fc & 1) * 512 + (fc >> 1) * 16) * 512;  // elem offset
        bf16x8 bf = *(const bf16x8*)(bbase + ofs + k0 + kh * 32);
        acc[0][fc] = __builtin_amdgcn_mfma_f32_16x16x32_bf16(af0, bf, acc[0][fc], 0, 0, 0);
        acc[1][fc] = __builtin_amdgcn_mfma_f32_16x16x32_bf16(af1, bf, acc[1][fc], 0, 0, 0);
      }
    }
  }

  // ---- epilogue: score(m) = sum_d (q + Prq)(k + Prk), all within-wave ----
  const float* qbase = qws + ((size_t)(b * 256 + i0)) * 512 + head * 64;
  const float* krow = kws + ((size_t)(b * 256 + j)) * 512 + head * 64;
  float kv[4];
#pragma unroll
  for (int dc = 0; dc < 4; ++dc) kv[dc] = krow[dc * 16 + t15];
#pragma unroll
  for (int fr = 0; fr < 2; ++fr) {
#pragma unroll
    for (int r = 0; r < 4; ++r) {
      int m = fr * 16 + q2 * 4 + r;
      float s = 0.f;
#pragma unroll
      for (int dc = 0; dc < 4; ++dc) {
        float qv = qbase[(size_t)m * 512 + dc * 16 + t15];
        s += (qv + acc[fr][dc * 2][r]) * (kv[dc] + acc[fr][dc * 2 + 1][r]);
      }
      s += __shfl_xor(s, 1);
      s += __shfl_xor(s, 2);
      s += __shfl_xor(s, 4);
      s += __shfl_xor(s, 8);
      if (t15 == 0)
        attn[(((size_t)(b * 256 + i0 + m)) * 256 + j) * 8 + head] = s;
    }
  }
}

// ===========================================================================
// Fused masked softmax (over j) + AV contraction.  Block = (b,i).
// Writes normalized weights to attn (output #2) and o1[b,i,:].
// ===========================================================================
__global__ __launch_bounds__(256) void softmax_av_kernel(
    float* __restrict__ attn, const int* __restrict__ adj,
    const float* __restrict__ vws, float* __restrict__ o1) {
  __shared__ float sl[2048];
  __shared__ int msk[256];
  int bi = blockIdx.x;                         // b*256 + i
  int b = bi >> 8;
  float* base = attn + (size_t)bi * 2048;
  const int* abase = adj + (size_t)bi * 256;
  int tid = threadIdx.x;
#pragma unroll
  for (int u = 0; u < 8; ++u) sl[tid + u * 256] = base[tid + u * 256];
  msk[tid] = abase[tid];
  __syncthreads();
  int h = tid >> 5, l5 = tid & 31;
  float mx = -INFINITY;
#pragma unroll
  for (int u = 0; u < 8; ++u) {
    int jj = l5 + u * 32;
    if (msk[jj] != 1) mx = fmaxf(mx, sl[jj * 8 + h]);
  }
#pragma unroll
  for (int off = 16; off >= 1; off >>= 1) mx = fmaxf(mx, __shfl_xor(mx, off));
  float ev[8];
  float sum = 0.f;
#pragma unroll
  for (int u = 0; u < 8; ++u) {
    int jj = l5 + u * 32;
    float e = (msk[jj] != 1) ? __expf(sl[jj * 8 + h] - mx) : 0.f;
    ev[u] = e;
    sum += e;
  }
#pragma unroll
  for (int off = 16; off >= 1; off >>= 1) sum += __shfl_xor(sum, off);
  float inv = (sum > 0.f) ? (1.f / sum) : 0.f;
#pragma unroll
  for (int u = 0; u < 8; ++u) {
    int jj = l5 + u * 32;
    sl[jj * 8 + h] = ev[u] * inv;
  }
  __syncthreads();
  // write normalized weights (output #2)
#pragma unroll
  for (int u = 0; u < 8; ++u) base[tid + u * 256] = sl[tid + u * 256];
  // AV from LDS weights
  const float* vbase = vws + (size_t)b * (256 * 512);
  int e0 = tid, e1 = tid + 256;
  int h0 = e0 >> 6, h1 = e1 >> 6;
  float a0 = 0.f, a1 = 0.f;
  for (int jj = 0; jj < 256; ++jj) {
    float w0 = sl[jj * 8 + h0];
    float w1 = sl[jj * 8 + h1];
    const float* vr = vbase + (size_t)jj * 512;
    a0 += w0 * vr[e0];
    a1 += w1 * vr[e1];
  }
  float* orow = o1 + (size_t)bi * 512;
  orow[e0] = a0;
  orow[e1] = a1;
}

// ===========================================================================
// Launch
// ===========================================================================
extern "C" void kernel_launch(void* const* d_in, const int* in_sizes, int n_in,
                              void* d_out, int out_size, void* d_ws, size_t ws_size,
                              hipStream_t stream) {
  const float* queries = (const float*)d_in[0];
  const float* keys    = (const float*)d_in[1];
  const float* values  = (const float*)d_in[2];
  const float* relation = (const float*)d_in[3];
  const int*   adj     = (const int*)d_in[4];
  const float* Wq = (const float*)d_in[5];
  const float* bq = (const float*)d_in[6];
  const float* Wk = (const float*)d_in[7];
  const float* bk = (const float*)d_in[8];
  const float* Wv = (const float*)d_in[9];
  const float* bv = (const float*)d_in[10];
  const float* Wr = (const float*)d_in[11];
  const float* Wo = (const float*)d_in[12];
  const float* bo = (const float*)d_in[13];

  float* out  = (float*)d_out;            // [2*256][512]
  float* attn = out + 262144;             // [2][256][256][8]

  float* ws  = (float*)d_ws;
  float* qws = ws;                        // 262144
  float* kws = ws + 262144;
  float* vws = ws + 524288;
  float* o1  = ws + 786432;
  unsigned short* wrbf = (unsigned short*)(ws + 1048576);  // 524288 bf16

  cvt_wr_kernel<<<dim3(512), dim3(256), 0, stream>>>(Wr, wrbf);

  proj_kernel<<<dim3(8, 8, 3), dim3(256), 0, stream>>>(
      queries, Wq, bq, qws,
      keys,    Wk, bk, kws,
      values,  Wv, bv, vws,
      0.125f);

  rel_score_kernel<<<dim3(8192), dim3(256), 0, stream>>>(relation, wrbf, qws, kws, attn);

  softmax_av_kernel<<<dim3(512), dim3(256), 0, stream>>>(attn, adj, vws, o1);

  proj_kernel<<<dim3(8, 8, 1), dim3(256), 0, stream>>>(
      o1, Wo, bo, out,
      nullptr, nullptr, nullptr, nullptr,
      nullptr, nullptr, nullptr, nullptr,
      1.0f);
}